// Round 1
// baseline (165.721 us; speedup 1.0000x reference)
//
#include <hip/hip_runtime.h>

namespace {
constexpr int Sdim = 128;
constexpr int Tdim = 64;
constexpr int U2c  = 16;
constexpr int PT   = 16;                 // pixel locations per block
constexpr int NTHREADS = 256;
constexpr int PP = Sdim * Sdim;          // 16384 pixels
}

__global__ __launch_bounds__(NTHREADS, 2)
void upscale_fused(const float* __restrict__ yt,
                   const float* __restrict__ wgt,
                   const float* __restrict__ bias,
                   float* __restrict__ out)
{
    // [t][u][p_local], p fastest: compute reads ds_read_b128 over 4 consecutive p,
    // 4 unique addrs/wave -> 16 banks, 16-lane broadcast, conflict-free. 64 KiB.
    __shared__ float wlds[Tdim * U2c * PT];

    const int tid   = threadIdx.x;
    const int p_blk = blockIdx.x * PT;

    // ---------------- stage weights into LDS (once; read exactly once from HBM) ----
    {
        const int sp = tid & (PT - 1);      // p_local 0..15
        const int sj = tid >> 4;            // 0..15: 64-float chunk within the p-row
        const float* src = wgt + (size_t)(p_blk + sp) * (Tdim * U2c) + sj * 64;
        #pragma unroll
        for (int k = 0; k < 16; ++k) {
            const float4 v = *reinterpret_cast<const float4*>(src + k * 4);
            const int off = sj * 64 + k * 4;          // = t*16 + u0, u0 in {0,4,8,12}
            wlds[(off + 0) * PT + sp] = v.x;
            wlds[(off + 1) * PT + sp] = v.y;
            wlds[(off + 2) * PT + sp] = v.z;
            wlds[(off + 3) * PT + sp] = v.w;
        }
    }
    __syncthreads();

    // ---------------- thread mapping: 4p x 2b x 8u per thread ----------------
    const int pg = tid & 3;            // p0 = p_blk + pg*4 .. +3
    const int b2 = (tid >> 2) & 31;    // b in {b2, b2+32}
    const int ug = tid >> 7;           // u = ug*8 + v, v in [0,8)
    const int p0 = p_blk + pg * 4;

    // ---------------- init acc with bias (same bias for both b) ----------------
    float acc[2][4][8];
    #pragma unroll
    for (int j = 0; j < 4; ++j) {
        const float* bp = bias + (size_t)(p0 + j) * U2c + ug * 8;
        const float4 v0 = *reinterpret_cast<const float4*>(bp);
        const float4 v1 = *reinterpret_cast<const float4*>(bp + 4);
        const float bb[8] = {v0.x, v0.y, v0.z, v0.w, v1.x, v1.y, v1.z, v1.w};
        #pragma unroll
        for (int v = 0; v < 8; ++v) { acc[0][j][v] = bb[v]; acc[1][j][v] = bb[v]; }
    }

    // ---------------- t-loop (the reduction), 2-deep yt prefetch ----------------
    const float* y0base = yt + (size_t)b2 * (Tdim * PP) + p0;
    const float* y1base = y0base + (size_t)32 * (Tdim * PP);

    float4 yc0 = *reinterpret_cast<const float4*>(y0base);
    float4 yc1 = *reinterpret_cast<const float4*>(y1base);
    float4 yn0 = *reinterpret_cast<const float4*>(y0base + PP);
    float4 yn1 = *reinterpret_cast<const float4*>(y1base + PP);

    for (int t = 0; t < Tdim; ++t) {
        const int tf = (t + 2 < Tdim) ? (t + 2) : (Tdim - 1);
        const float4 yf0 = *reinterpret_cast<const float4*>(y0base + (size_t)tf * PP);
        const float4 yf1 = *reinterpret_cast<const float4*>(y1base + (size_t)tf * PP);

        const float ya[4] = {yc0.x, yc0.y, yc0.z, yc0.w};
        const float yb[4] = {yc1.x, yc1.y, yc1.z, yc1.w};

        const float* wrow = &wlds[(size_t)(t * U2c + ug * 8) * PT + pg * 4];
        #pragma unroll
        for (int v = 0; v < 8; ++v) {
            const float4 wv = *reinterpret_cast<const float4*>(wrow + v * PT);
            acc[0][0][v] = fmaf(ya[0], wv.x, acc[0][0][v]);
            acc[0][1][v] = fmaf(ya[1], wv.y, acc[0][1][v]);
            acc[0][2][v] = fmaf(ya[2], wv.z, acc[0][2][v]);
            acc[0][3][v] = fmaf(ya[3], wv.w, acc[0][3][v]);
            acc[1][0][v] = fmaf(yb[0], wv.x, acc[1][0][v]);
            acc[1][1][v] = fmaf(yb[1], wv.y, acc[1][1][v]);
            acc[1][2][v] = fmaf(yb[2], wv.z, acc[1][2][v]);
            acc[1][3][v] = fmaf(yb[3], wv.w, acc[1][3][v]);
        }
        yc0 = yn0; yc1 = yn1; yn0 = yf0; yn1 = yf1;
    }

    // ---------------- epilogue: pixel-shuffle scatter, 64B contiguous per lane ----
    const int s1   = p_blk / Sdim;
    const int s2_0 = p_blk % Sdim;

    #pragma unroll
    for (int bi = 0; bi < 2; ++bi) {
        const int b = b2 + bi * 32;
        float* ob = out + (size_t)b * (512 * 512);
        #pragma unroll
        for (int u1l = 0; u1l < 2; ++u1l) {
            const int r = s1 * 4 + (ug * 2 + u1l);
            #pragma unroll
            for (int j = 0; j < 4; ++j) {
                const int c0 = (s2_0 + pg * 4 + j) * 4;
                float4 v;
                v.x = acc[bi][j][u1l * 4 + 0];
                v.y = acc[bi][j][u1l * 4 + 1];
                v.z = acc[bi][j][u1l * 4 + 2];
                v.w = acc[bi][j][u1l * 4 + 3];
                *reinterpret_cast<float4*>(ob + (size_t)r * 512 + c0) = v;
            }
        }
    }
}

extern "C" void kernel_launch(void* const* d_in, const int* in_sizes, int n_in,
                              void* d_out, int out_size, void* d_ws, size_t ws_size,
                              hipStream_t stream)
{
    const float* yt   = (const float*)d_in[0];
    const float* wgt  = (const float*)d_in[1];
    const float* bias = (const float*)d_in[2];
    float* outp       = (float*)d_out;

    dim3 grid(PP / PT);     // 1024 blocks
    dim3 block(NTHREADS);
    hipLaunchKernelGGL(upscale_fused, grid, block, 0, stream, yt, wgt, bias, outp);
}